// Round 1
// baseline (462.317 us; speedup 1.0000x reference)
//
#include <hip/hip_runtime.h>
#include <hip/hip_bf16.h>
#include <cstdint>

typedef _Float16 f16;
typedef __attribute__((ext_vector_type(8))) _Float16 f16x8;
typedef __attribute__((ext_vector_type(4))) _Float16 f16x4;
typedef __attribute__((ext_vector_type(4))) float f32x4;

#define MFMA(a, b, c) __builtin_amdgcn_mfma_f32_16x16x32_f16((a), (b), (c), 0, 0, 0)

__device__ static inline void gl_lds16(const void* g, void* l) {
  __builtin_amdgcn_global_load_lds(
      (__attribute__((address_space(1))) const void*)g,
      (__attribute__((address_space(3))) void*)l, 16, 0, 0);
}

// ---------------- f32 -> f16 cast, 4-wide ----------------
__global__ __launch_bounds__(256) void cvt_f16(const float* __restrict__ in,
                                               f16* __restrict__ out, int n4) {
  int i = blockIdx.x * 256 + threadIdx.x;
  if (i >= n4) return;
  const float4 v = reinterpret_cast<const float4*>(in)[i];
  f16x4 o;
  o.x = (f16)v.x; o.y = (f16)v.y; o.z = (f16)v.z; o.w = (f16)v.w;
  reinterpret_cast<f16x4*>(out)[i] = o;
}

// ---------------- QKV GEMM: [8192,768] x [2304,768]^T ----------------
// C written scattered: Q,K as [B,H,N,D] (Q pre-scaled by SCALE*log2e), V as [B,H,D,N]
__global__ __launch_bounds__(256) void gemm_qkv(const f16* __restrict__ X,
                                                const f16* __restrict__ W,
                                                f16* __restrict__ Q,
                                                f16* __restrict__ Ko,
                                                f16* __restrict__ Vt) {
  __shared__ f16 As[128 * 64];
  __shared__ f16 Bs[128 * 64];
  const int tid = threadIdx.x;
  const int lane = tid & 63;
  const int w = tid >> 6;
  const int m0 = blockIdx.x * 128;
  const int n0 = blockIdx.y * 128;
  const int wr = (w >> 1) * 64;
  const int wc = (w & 1) * 64;
  const int srow = lane >> 3;       // 0..7 (row within 8-row chunk)
  const int scol = (lane & 7) * 8;  // f16 offset within row
  f32x4 acc[4][4] = {};

  for (int k0 = 0; k0 < 768; k0 += 64) {
#pragma unroll
    for (int i = 0; i < 4; ++i) {
      const int c = w * 4 + i;
      const int row = c * 8 + srow;
      gl_lds16(X + (size_t)(m0 + row) * 768 + k0 + scol, &As[c * 512]);
      gl_lds16(W + (size_t)(n0 + row) * 768 + k0 + scol, &Bs[c * 512]);
    }
    __syncthreads();
#pragma unroll
    for (int kk = 0; kk < 2; ++kk) {
      const int ko = kk * 32 + (lane >> 4) * 8;
      f16x8 af[4], bf[4];
#pragma unroll
      for (int i = 0; i < 4; ++i)
        af[i] = *reinterpret_cast<const f16x8*>(&As[(wr + i * 16 + (lane & 15)) * 64 + ko]);
#pragma unroll
      for (int j = 0; j < 4; ++j)
        bf[j] = *reinterpret_cast<const f16x8*>(&Bs[(wc + j * 16 + (lane & 15)) * 64 + ko]);
#pragma unroll
      for (int i = 0; i < 4; ++i)
#pragma unroll
        for (int j = 0; j < 4; ++j)
          acc[i][j] = MFMA(af[i], bf[j], acc[i][j]);
    }
    __syncthreads();
  }

  // epilogue: scatter into Q/K/V head layouts
  const int b = m0 >> 11;                       // 2048 rows per batch, 128 | 2048
  const int nbase = (m0 & 2047) + wr;
  const int which = n0 / 768;                   // uniform per block (128 | 768)
  const int h = ((n0 % 768) >> 6) + (wc >> 6);  // head, uniform per wave
  const float QSCL = 0.125f * 1.44269504088896340736f;  // SCALE * log2(e)
#pragma unroll
  for (int i = 0; i < 4; ++i) {
#pragma unroll
    for (int j = 0; j < 4; ++j) {
      const int d = j * 16 + (lane & 15);
#pragma unroll
      for (int r = 0; r < 4; ++r) {
        const int n = nbase + i * 16 + (lane >> 4) * 4 + r;
        const float v = acc[i][j][r];
        if (which == 0) {
          Q[(((size_t)(b * 12 + h)) * 2048 + n) * 64 + d] = (f16)(v * QSCL);
        } else if (which == 1) {
          Ko[(((size_t)(b * 12 + h)) * 2048 + n) * 64 + d] = (f16)v;
        } else {
          Vt[(((size_t)(b * 12 + h)) * 64 + d) * 2048 + n] = (f16)v;
        }
      }
    }
  }
}

// ---------------- flash attention ----------------
// grid (16, 48): x = 128-row Q tile, y = b*12+h. 4 waves, 32 Q-rows per wave.
__global__ __launch_bounds__(256) void attn_fwd(const f16* __restrict__ Q,
                                                const f16* __restrict__ K,
                                                const f16* __restrict__ Vt,
                                                f16* __restrict__ Ao) {
  __shared__ f16 Ps[4][32][40];  // per-wave P transpose buffer (pad 40 vs 32)
  const int tid = threadIdx.x, lane = tid & 63, w = tid >> 6;
  const int bh = blockIdx.y;
  const int b = bh / 12, h = bh % 12;
  const int q0 = blockIdx.x * 128 + w * 32;
  const f16* Qp = Q + (size_t)bh * 2048 * 64;
  const f16* Kp = K + (size_t)bh * 2048 * 64;
  const f16* Vp = Vt + (size_t)bh * 64 * 2048;

  f16x8 qf[2][2];
#pragma unroll
  for (int mi = 0; mi < 2; ++mi)
#pragma unroll
    for (int kk = 0; kk < 2; ++kk)
      qf[mi][kk] = *reinterpret_cast<const f16x8*>(
          &Qp[(size_t)(q0 + mi * 16 + (lane & 15)) * 64 + kk * 32 + (lane >> 4) * 8]);

  f32x4 o[2][4] = {};
  float mrun[2][4], lrun[2][4];
#pragma unroll
  for (int mi = 0; mi < 2; ++mi)
#pragma unroll
    for (int r = 0; r < 4; ++r) { mrun[mi][r] = -1e30f; lrun[mi][r] = 0.f; }

  for (int kv = 0; kv < 2048; kv += 32) {
    // ---- S = Q K^T (pre-scaled; logits already in log2 domain) ----
    f16x8 kf[2][2];
#pragma unroll
    for (int nj = 0; nj < 2; ++nj)
#pragma unroll
      for (int kk = 0; kk < 2; ++kk)
        kf[nj][kk] = *reinterpret_cast<const f16x8*>(
            &Kp[(size_t)(kv + nj * 16 + (lane & 15)) * 64 + kk * 32 + (lane >> 4) * 8]);
    f32x4 s[2][2] = {};
#pragma unroll
    for (int mi = 0; mi < 2; ++mi)
#pragma unroll
      for (int nj = 0; nj < 2; ++nj)
#pragma unroll
        for (int kk = 0; kk < 2; ++kk)
          s[mi][nj] = MFMA(qf[mi][kk], kf[nj][kk], s[mi][nj]);

    // ---- online softmax; row of element r = (lane>>4)*4 + r ----
#pragma unroll
    for (int mi = 0; mi < 2; ++mi) {
#pragma unroll
      for (int r = 0; r < 4; ++r) {
        float tm = fmaxf(s[mi][0][r], s[mi][1][r]);
#pragma unroll
        for (int d = 1; d < 16; d <<= 1) tm = fmaxf(tm, __shfl_xor(tm, d));
        const float nm = fmaxf(mrun[mi][r], tm);
        const float corr = exp2f(mrun[mi][r] - nm);
        const float p0 = exp2f(s[mi][0][r] - nm);
        const float p1 = exp2f(s[mi][1][r] - nm);
        float rs = p0 + p1;
#pragma unroll
        for (int d = 1; d < 16; d <<= 1) rs += __shfl_xor(rs, d);
        mrun[mi][r] = nm;
        lrun[mi][r] = lrun[mi][r] * corr + rs;
        s[mi][0][r] = p0;
        s[mi][1][r] = p1;
#pragma unroll
        for (int j = 0; j < 4; ++j) o[mi][j][r] *= corr;
      }
    }
    // ---- P -> LDS (C-layout -> A-layout transpose), per-wave region ----
#pragma unroll
    for (int mi = 0; mi < 2; ++mi)
#pragma unroll
      for (int nj = 0; nj < 2; ++nj)
#pragma unroll
        for (int r = 0; r < 4; ++r)
          Ps[w][mi * 16 + (lane >> 4) * 4 + r][nj * 16 + (lane & 15)] = (f16)s[mi][nj][r];
    __syncthreads();
    // ---- O += P V ----
    f16x8 vf[4];
#pragma unroll
    for (int j = 0; j < 4; ++j)
      vf[j] = *reinterpret_cast<const f16x8*>(
          &Vp[(size_t)(j * 16 + (lane & 15)) * 2048 + kv + (lane >> 4) * 8]);
#pragma unroll
    for (int mi = 0; mi < 2; ++mi) {
      const f16x8 af = *reinterpret_cast<const f16x8*>(&Ps[w][mi * 16 + (lane & 15)][(lane >> 4) * 8]);
#pragma unroll
      for (int j = 0; j < 4; ++j) o[mi][j] = MFMA(af, vf[j], o[mi][j]);
    }
  }
  // epilogue: write attn_out as [B, N, H*D]
#pragma unroll
  for (int mi = 0; mi < 2; ++mi)
#pragma unroll
    for (int r = 0; r < 4; ++r) {
      const float inv = 1.0f / lrun[mi][r];
      const int n = q0 + mi * 16 + (lane >> 4) * 4 + r;
#pragma unroll
      for (int j = 0; j < 4; ++j)
        Ao[((size_t)(b * 2048 + n)) * 768 + h * 64 + j * 16 + (lane & 15)] =
            (f16)(o[mi][j][r] * inv);
    }
}

// ---------------- proj GEMM: [8192,768] x [768,768]^T + bias -> f32 ----------------
__global__ __launch_bounds__(256) void gemm_proj(const f16* __restrict__ A,
                                                 const f16* __restrict__ W,
                                                 const float* __restrict__ bias,
                                                 float* __restrict__ out) {
  __shared__ f16 As[128 * 64];
  __shared__ f16 Bs[128 * 64];
  const int tid = threadIdx.x;
  const int lane = tid & 63;
  const int w = tid >> 6;
  const int m0 = blockIdx.x * 128;
  const int n0 = blockIdx.y * 128;
  const int wr = (w >> 1) * 64;
  const int wc = (w & 1) * 64;
  const int srow = lane >> 3;
  const int scol = (lane & 7) * 8;
  f32x4 acc[4][4] = {};

  for (int k0 = 0; k0 < 768; k0 += 64) {
#pragma unroll
    for (int i = 0; i < 4; ++i) {
      const int c = w * 4 + i;
      const int row = c * 8 + srow;
      gl_lds16(A + (size_t)(m0 + row) * 768 + k0 + scol, &As[c * 512]);
      gl_lds16(W + (size_t)(n0 + row) * 768 + k0 + scol, &Bs[c * 512]);
    }
    __syncthreads();
#pragma unroll
    for (int kk = 0; kk < 2; ++kk) {
      const int ko = kk * 32 + (lane >> 4) * 8;
      f16x8 af[4], bf[4];
#pragma unroll
      for (int i = 0; i < 4; ++i)
        af[i] = *reinterpret_cast<const f16x8*>(&As[(wr + i * 16 + (lane & 15)) * 64 + ko]);
#pragma unroll
      for (int j = 0; j < 4; ++j)
        bf[j] = *reinterpret_cast<const f16x8*>(&Bs[(wc + j * 16 + (lane & 15)) * 64 + ko]);
#pragma unroll
      for (int i = 0; i < 4; ++i)
#pragma unroll
        for (int j = 0; j < 4; ++j)
          acc[i][j] = MFMA(af[i], bf[j], acc[i][j]);
    }
    __syncthreads();
  }

#pragma unroll
  for (int j = 0; j < 4; ++j) {
    const int col = n0 + wc + j * 16 + (lane & 15);
    const float bj = bias[col];
#pragma unroll
    for (int i = 0; i < 4; ++i)
#pragma unroll
      for (int r = 0; r < 4; ++r)
        out[(size_t)(m0 + wr + i * 16 + (lane >> 4) * 4 + r) * 768 + col] =
            acc[i][j][r] + bj;
  }
}

extern "C" void kernel_launch(void* const* d_in, const int* in_sizes, int n_in,
                              void* d_out, int out_size, void* d_ws, size_t ws_size,
                              hipStream_t stream) {
  const float* x      = (const float*)d_in[0];  // [4,2048,768]
  const float* w_qkv  = (const float*)d_in[1];  // [2304,768]
  const float* w_proj = (const float*)d_in[2];  // [768,768]
  const float* b_proj = (const float*)d_in[3];  // [768]
  float* out = (float*)d_out;
  char* ws = (char*)d_ws;

  f16* xh  = (f16*)(ws);              // 8192*768*2      = 12,582,912
  f16* wqh = (f16*)(ws + 12582912);   // 2304*768*2      =  3,538,944
  f16* wph = (f16*)(ws + 16121856);   // 768*768*2       =  1,179,648
  f16* Qb  = (f16*)(ws + 17301504);   // [4,12,2048,64]  = 12,582,912
  f16* Kb  = (f16*)(ws + 29884416);   // [4,12,2048,64]
  f16* Vtb = (f16*)(ws + 42467328);   // [4,12,64,2048]
  f16* Ah  = (f16*)(ws + 55050240);   // [4,2048,768]    -> total 67,633,152 B

  cvt_f16<<<6144, 256, 0, stream>>>(x, xh, 1572864);
  cvt_f16<<<1728, 256, 0, stream>>>(w_qkv, wqh, 442368);
  cvt_f16<<<576, 256, 0, stream>>>(w_proj, wph, 147456);

  gemm_qkv<<<dim3(64, 18), 256, 0, stream>>>(xh, wqh, Qb, Kb, Vtb);
  attn_fwd<<<dim3(16, 48), 256, 0, stream>>>(Qb, Kb, Vtb, Ah);
  gemm_proj<<<dim3(64, 6), 256, 0, stream>>>(Ah, wph, b_proj, out);
}

// Round 2
// 286.811 us; speedup vs baseline: 1.6119x; 1.6119x over previous
//
#include <hip/hip_runtime.h>
#include <hip/hip_bf16.h>
#include <cstdint>

typedef _Float16 f16;
typedef __attribute__((ext_vector_type(8))) _Float16 f16x8;
typedef __attribute__((ext_vector_type(4))) _Float16 f16x4;
typedef __attribute__((ext_vector_type(4))) float f32x4;

#define MFMA(a, b, c) __builtin_amdgcn_mfma_f32_16x16x32_f16((a), (b), (c), 0, 0, 0)

__device__ static inline void gl_lds16(const void* g, void* l) {
  __builtin_amdgcn_global_load_lds(
      (__attribute__((address_space(1))) const void*)g,
      (__attribute__((address_space(3))) void*)l, 16, 0, 0);
}

// ---------------- f32 -> f16 cast, 4-wide ----------------
__global__ __launch_bounds__(256) void cvt_f16(const float* __restrict__ in,
                                               f16* __restrict__ out, int n4) {
  int i = blockIdx.x * 256 + threadIdx.x;
  if (i >= n4) return;
  const float4 v = reinterpret_cast<const float4*>(in)[i];
  f16x4 o;
  o.x = (f16)v.x; o.y = (f16)v.y; o.z = (f16)v.z; o.w = (f16)v.w;
  reinterpret_cast<f16x4*>(out)[i] = o;
}

// ---------------- QKV GEMM: [8192,768] x [2304,768]^T ----------------
// C written scattered: Q,K as [B,H,N,D] (Q pre-scaled by SCALE*log2e), V as [B,H,D,N]
__global__ __launch_bounds__(256) void gemm_qkv(const f16* __restrict__ X,
                                                const f16* __restrict__ W,
                                                f16* __restrict__ Q,
                                                f16* __restrict__ Ko,
                                                f16* __restrict__ Vt) {
  __shared__ f16 As[128 * 64];
  __shared__ f16 Bs[128 * 64];
  const int tid = threadIdx.x;
  const int lane = tid & 63;
  const int w = tid >> 6;
  const int m0 = blockIdx.x * 128;
  const int n0 = blockIdx.y * 128;
  const int wr = (w >> 1) * 64;
  const int wc = (w & 1) * 64;
  const int srow = lane >> 3;       // 0..7 (row within 8-row chunk)
  const int scol = (lane & 7) * 8;  // f16 offset within row
  f32x4 acc[4][4] = {};

  for (int k0 = 0; k0 < 768; k0 += 64) {
#pragma unroll
    for (int i = 0; i < 4; ++i) {
      const int c = w * 4 + i;
      const int row = c * 8 + srow;
      gl_lds16(X + (size_t)(m0 + row) * 768 + k0 + scol, &As[c * 512]);
      gl_lds16(W + (size_t)(n0 + row) * 768 + k0 + scol, &Bs[c * 512]);
    }
    __syncthreads();
#pragma unroll
    for (int kk = 0; kk < 2; ++kk) {
      const int ko = kk * 32 + (lane >> 4) * 8;
      f16x8 af[4], bf[4];
#pragma unroll
      for (int i = 0; i < 4; ++i)
        af[i] = *reinterpret_cast<const f16x8*>(&As[(wr + i * 16 + (lane & 15)) * 64 + ko]);
#pragma unroll
      for (int j = 0; j < 4; ++j)
        bf[j] = *reinterpret_cast<const f16x8*>(&Bs[(wc + j * 16 + (lane & 15)) * 64 + ko]);
#pragma unroll
      for (int i = 0; i < 4; ++i)
#pragma unroll
        for (int j = 0; j < 4; ++j)
          acc[i][j] = MFMA(af[i], bf[j], acc[i][j]);
    }
    __syncthreads();
  }

  // epilogue: scatter into Q/K/V head layouts
  const int b = m0 >> 11;                       // 2048 rows per batch, 128 | 2048
  const int nbase = (m0 & 2047) + wr;
  const int which = n0 / 768;                   // uniform per block (128 | 768)
  const int h = ((n0 % 768) >> 6) + (wc >> 6);  // head, uniform per wave
  const float QSCL = 0.125f * 1.44269504088896340736f;  // SCALE * log2(e)
#pragma unroll
  for (int i = 0; i < 4; ++i) {
#pragma unroll
    for (int j = 0; j < 4; ++j) {
      const int d = j * 16 + (lane & 15);
#pragma unroll
      for (int r = 0; r < 4; ++r) {
        const int n = nbase + i * 16 + (lane >> 4) * 4 + r;
        const float v = acc[i][j][r];
        if (which == 0) {
          Q[(((size_t)(b * 12 + h)) * 2048 + n) * 64 + d] = (f16)(v * QSCL);
        } else if (which == 1) {
          Ko[(((size_t)(b * 12 + h)) * 2048 + n) * 64 + d] = (f16)v;
        } else {
          Vt[(((size_t)(b * 12 + h)) * 64 + d) * 2048 + n] = (f16)v;
        }
      }
    }
  }
}

// ---------------- flash attention, swapped-operand form ----------------
// 1 wave per block, 32 Q rows per wave, KVBLK=64, K double-buffered in regs.
// S^T = mfma(K,Q): lane holds S^T[kv][q=lane&15]; softmax mostly in-lane.
// O^T = mfma(V^T,P): lane holds O^T[d][q=lane&15]; rescale lane-local.
__device__ __forceinline__ void attn_step(
    const f16* __restrict__ Kp, const f16* __restrict__ Vp, int lane,
    const f16x8 (&qf)[2][2], const f16x8 (&kf)[4][2], f16x8 (&kfn)[4][2],
    int kv, int kvn, f16* Ps, f32x4 (&o)[4][2], float (&mrun)[2],
    float (&lrun)[2]) {
  // ---- S^T = K Q^T ----
  f32x4 s[4][2] = {};
#pragma unroll
  for (int nj = 0; nj < 4; ++nj)
#pragma unroll
    for (int kk = 0; kk < 2; ++kk)
#pragma unroll
      for (int mi = 0; mi < 2; ++mi)
        s[nj][mi] = MFMA(kf[nj][kk], qf[mi][kk], s[nj][mi]);
  // ---- prefetch next K tile (consumed next step) ----
#pragma unroll
  for (int nj = 0; nj < 4; ++nj)
#pragma unroll
    for (int kk = 0; kk < 2; ++kk)
      kfn[nj][kk] = *reinterpret_cast<const f16x8*>(
          &Kp[(size_t)(kvn + nj * 16 + (lane & 15)) * 64 + kk * 32 + (lane >> 4) * 8]);
  // ---- V fragments for this tile (latency hidden under softmax) ----
  f16x8 vf[4][2];
#pragma unroll
  for (int j = 0; j < 4; ++j)
#pragma unroll
    for (int kk = 0; kk < 2; ++kk)
      vf[j][kk] = *reinterpret_cast<const f16x8*>(
          &Vp[(size_t)(j * 16 + (lane & 15)) * 2048 + kv + kk * 32 + (lane >> 4) * 8]);
  // ---- online softmax; q = lane&15 per mi tile; kv spread in-lane + lane>>4 ----
#pragma unroll
  for (int mi = 0; mi < 2; ++mi) {
    float tm = s[0][mi][0];
#pragma unroll
    for (int nj = 0; nj < 4; ++nj)
#pragma unroll
      for (int r = 0; r < 4; ++r) tm = fmaxf(tm, s[nj][mi][r]);
    tm = fmaxf(tm, __shfl_xor(tm, 16));
    tm = fmaxf(tm, __shfl_xor(tm, 32));
    const bool resc = !__all(tm <= mrun[mi] + 8.0f);  // defer-max (T13)
    float nm = mrun[mi];
    if (resc) nm = fmaxf(mrun[mi], tm);
    float rs = 0.f;
#pragma unroll
    for (int nj = 0; nj < 4; ++nj) {
      f16x4 pk;
#pragma unroll
      for (int r = 0; r < 4; ++r) {
        const float p = exp2f(s[nj][mi][r] - nm);
        rs += p;
        pk[r] = (f16)p;
      }
      *reinterpret_cast<f16x4*>(
          &Ps[(mi * 16 + (lane & 15)) * 72 + nj * 16 + (lane >> 4) * 4]) = pk;
    }
    rs += __shfl_xor(rs, 16);
    rs += __shfl_xor(rs, 32);
    if (resc) {
      const float corr = exp2f(mrun[mi] - nm);
      lrun[mi] = lrun[mi] * corr + rs;
      mrun[mi] = nm;
#pragma unroll
      for (int j = 0; j < 4; ++j)
#pragma unroll
        for (int r = 0; r < 4; ++r) o[j][mi][r] *= corr;
    } else {
      lrun[mi] += rs;
    }
  }
  __syncthreads();  // single-wave block: just orders LDS write->read
  // ---- O^T += V^T P ----
#pragma unroll
  for (int mi = 0; mi < 2; ++mi) {
    f16x8 pf[2];
#pragma unroll
    for (int kk = 0; kk < 2; ++kk)
      pf[kk] = *reinterpret_cast<const f16x8*>(
          &Ps[(mi * 16 + (lane & 15)) * 72 + kk * 32 + (lane >> 4) * 8]);
#pragma unroll
    for (int j = 0; j < 4; ++j)
#pragma unroll
      for (int kk = 0; kk < 2; ++kk)
        o[j][mi] = MFMA(vf[j][kk], pf[kk], o[j][mi]);
  }
}

__global__ __launch_bounds__(64) void attn_fwd(const f16* __restrict__ Q,
                                               const f16* __restrict__ K,
                                               const f16* __restrict__ Vt,
                                               f16* __restrict__ Ao) {
  __shared__ f16 Ps[32 * 72];
  const int lane = threadIdx.x;
  const int bh = blockIdx.y;
  const int b = bh / 12, h = bh % 12;
  const int q0 = blockIdx.x * 32;
  const f16* Qp = Q + (size_t)bh * 2048 * 64;
  const f16* Kp = K + (size_t)bh * 2048 * 64;
  const f16* Vp = Vt + (size_t)bh * 64 * 2048;

  f16x8 qf[2][2];
#pragma unroll
  for (int mi = 0; mi < 2; ++mi)
#pragma unroll
    for (int kk = 0; kk < 2; ++kk)
      qf[mi][kk] = *reinterpret_cast<const f16x8*>(
          &Qp[(size_t)(q0 + mi * 16 + (lane & 15)) * 64 + kk * 32 + (lane >> 4) * 8]);

  f32x4 o[4][2] = {};
  float mrun[2] = {-1e30f, -1e30f}, lrun[2] = {0.f, 0.f};

  f16x8 kfA[4][2], kfB[4][2];
#pragma unroll
  for (int nj = 0; nj < 4; ++nj)
#pragma unroll
    for (int kk = 0; kk < 2; ++kk)
      kfA[nj][kk] = *reinterpret_cast<const f16x8*>(
          &Kp[(size_t)(nj * 16 + (lane & 15)) * 64 + kk * 32 + (lane >> 4) * 8]);

  for (int kv = 0; kv < 2048; kv += 128) {
    attn_step(Kp, Vp, lane, qf, kfA, kfB, kv, kv + 64, Ps, o, mrun, lrun);
    attn_step(Kp, Vp, lane, qf, kfB, kfA, kv + 64, (kv + 128) & 2047, Ps, o,
              mrun, lrun);
  }

  // ---- epilogue: normalize, transpose O^T -> O via LDS, coalesced store ----
  const float invl0 = 1.f / lrun[0], invl1 = 1.f / lrun[1];
#pragma unroll
  for (int mi = 0; mi < 2; ++mi) {
    const float inv = mi ? invl1 : invl0;
#pragma unroll
    for (int j = 0; j < 4; ++j) {
      f16x4 ok;
#pragma unroll
      for (int r = 0; r < 4; ++r) ok[r] = (f16)(o[j][mi][r] * inv);
      *reinterpret_cast<f16x4*>(
          &Ps[(mi * 16 + (lane & 15)) * 72 + j * 16 + (lane >> 4) * 4]) = ok;
    }
  }
  __syncthreads();
  const int ql = lane & 31, hh = lane >> 5;
#pragma unroll
  for (int t = 0; t < 4; ++t) {
    const f16x8 v = *reinterpret_cast<const f16x8*>(&Ps[ql * 72 + hh * 32 + t * 8]);
    *reinterpret_cast<f16x8*>(
        &Ao[((size_t)(b * 2048 + q0 + ql)) * 768 + h * 64 + hh * 32 + t * 8]) = v;
  }
}

// ---------------- proj GEMM: [8192,768] x [768,768]^T + bias -> f32 ----------------
__global__ __launch_bounds__(256) void gemm_proj(const f16* __restrict__ A,
                                                 const f16* __restrict__ W,
                                                 const float* __restrict__ bias,
                                                 float* __restrict__ out) {
  __shared__ f16 As[128 * 64];
  __shared__ f16 Bs[128 * 64];
  const int tid = threadIdx.x;
  const int lane = tid & 63;
  const int w = tid >> 6;
  const int m0 = blockIdx.x * 128;
  const int n0 = blockIdx.y * 128;
  const int wr = (w >> 1) * 64;
  const int wc = (w & 1) * 64;
  const int srow = lane >> 3;
  const int scol = (lane & 7) * 8;
  f32x4 acc[4][4] = {};

  for (int k0 = 0; k0 < 768; k0 += 64) {
#pragma unroll
    for (int i = 0; i < 4; ++i) {
      const int c = w * 4 + i;
      const int row = c * 8 + srow;
      gl_lds16(A + (size_t)(m0 + row) * 768 + k0 + scol, &As[c * 512]);
      gl_lds16(W + (size_t)(n0 + row) * 768 + k0 + scol, &Bs[c * 512]);
    }
    __syncthreads();
#pragma unroll
    for (int kk = 0; kk < 2; ++kk) {
      const int ko = kk * 32 + (lane >> 4) * 8;
      f16x8 af[4], bf[4];
#pragma unroll
      for (int i = 0; i < 4; ++i)
        af[i] = *reinterpret_cast<const f16x8*>(&As[(wr + i * 16 + (lane & 15)) * 64 + ko]);
#pragma unroll
      for (int j = 0; j < 4; ++j)
        bf[j] = *reinterpret_cast<const f16x8*>(&Bs[(wc + j * 16 + (lane & 15)) * 64 + ko]);
#pragma unroll
      for (int i = 0; i < 4; ++i)
#pragma unroll
        for (int j = 0; j < 4; ++j)
          acc[i][j] = MFMA(af[i], bf[j], acc[i][j]);
    }
    __syncthreads();
  }

#pragma unroll
  for (int j = 0; j < 4; ++j) {
    const int col = n0 + wc + j * 16 + (lane & 15);
    const float bj = bias[col];
#pragma unroll
    for (int i = 0; i < 4; ++i)
#pragma unroll
      for (int r = 0; r < 4; ++r)
        out[(size_t)(m0 + wr + i * 16 + (lane >> 4) * 4 + r) * 768 + col] =
            acc[i][j][r] + bj;
  }
}

extern "C" void kernel_launch(void* const* d_in, const int* in_sizes, int n_in,
                              void* d_out, int out_size, void* d_ws, size_t ws_size,
                              hipStream_t stream) {
  const float* x      = (const float*)d_in[0];  // [4,2048,768]
  const float* w_qkv  = (const float*)d_in[1];  // [2304,768]
  const float* w_proj = (const float*)d_in[2];  // [768,768]
  const float* b_proj = (const float*)d_in[3];  // [768]
  float* out = (float*)d_out;
  char* ws = (char*)d_ws;

  f16* xh  = (f16*)(ws);              // 8192*768*2      = 12,582,912
  f16* wqh = (f16*)(ws + 12582912);   // 2304*768*2      =  3,538,944
  f16* wph = (f16*)(ws + 16121856);   // 768*768*2       =  1,179,648
  f16* Qb  = (f16*)(ws + 17301504);   // [4,12,2048,64]  = 12,582,912
  f16* Kb  = (f16*)(ws + 29884416);   // [4,12,2048,64]
  f16* Vtb = (f16*)(ws + 42467328);   // [4,12,64,2048]
  f16* Ah  = (f16*)(ws + 55050240);   // [4,2048,768]    -> total 67,633,152 B

  cvt_f16<<<6144, 256, 0, stream>>>(x, xh, 1572864);
  cvt_f16<<<1728, 256, 0, stream>>>(w_qkv, wqh, 442368);
  cvt_f16<<<576, 256, 0, stream>>>(w_proj, wph, 147456);

  gemm_qkv<<<dim3(64, 18), 256, 0, stream>>>(xh, wqh, Qb, Kb, Vtb);
  attn_fwd<<<dim3(64, 48), 64, 0, stream>>>(Qb, Kb, Vtb, Ah);
  gemm_proj<<<dim3(64, 6), 256, 0, stream>>>(Ah, wph, b_proj, out);
}